// Round 4
// baseline (7835.972 us; speedup 1.0000x reference)
//
#include <hip/hip_runtime.h>

#define IDIM 128
#define ODIM 128
#define NH   8
#define DQH  32      // 2*ODIM/NH
#define EPSV 1e-10f

__device__ __forceinline__ float leaky(float w) { return w > 0.f ? w : 0.2f * w; }

// order-preserving float <-> u32 encoding for atomicMax
__device__ __forceinline__ unsigned encf(float f) {
  unsigned b = __float_as_uint(f);
  return (b & 0x80000000u) ? ~b : (b | 0x80000000u);
}
__device__ __forceinline__ float decf(unsigned e) {
  unsigned b = (e & 0x80000000u) ? (e & 0x7fffffffu) : ~e;
  return __uint_as_float(b);
}

// ---------------------------------------------------------------------------
// qWe[r][h][d] = sum_j query[r,h,2j]   * W[r][16h+j][d]
// qWo[r][h][d] = sum_j query[r,h,2j+1] * W[r][16h+j][d]
// ---------------------------------------------------------------------------
__global__ __launch_bounds__(256) void k_qw(
    const float* __restrict__ W, const float* __restrict__ query,
    float* __restrict__ qWe, float* __restrict__ qWo, int total) {
  int idx = blockIdx.x * 256 + threadIdx.x;
  if (idx >= total) return;
  int d  = idx & 127;
  int rh = idx >> 7;              // r*8+h
  int r = rh >> 3, h = rh & 7;
  const float* q  = query + (size_t)rh * DQH;
  const float* Wb = W + ((size_t)r * ODIM + h * 16) * IDIM + d;
  float se = 0.f, so = 0.f;
  #pragma unroll
  for (int j = 0; j < 16; ++j) {
    float wv = Wb[(size_t)j * IDIM];
    se += q[2 * j] * wv;
    so += q[2 * j + 1] * wv;
  }
  qWe[idx] = se;
  qWo[idx] = so;
}

// ---------------------------------------------------------------------------
// A[r][n][h] = qWe[r][h][:] . x[n][:]   ;   B likewise with qWo
// block = 256 thr = 16 nodes x 16 lanes; lanes stride the 72 (r,h) pairs
// ---------------------------------------------------------------------------
__global__ __launch_bounds__(256) void k_AB(
    const float* __restrict__ x, const float* __restrict__ qWe,
    const float* __restrict__ qWo, float* __restrict__ A, float* __restrict__ B,
    int N, int Rp1) {
  __shared__ float xs[16][132];
  const int n0 = blockIdx.x * 16;
  const int t = threadIdx.x;
  for (int i = t; i < 16 * 32; i += 256) {
    int node = i >> 5, c4 = i & 31;
    int n = n0 + node;
    float4 v = make_float4(0.f, 0.f, 0.f, 0.f);
    if (n < N) v = *(const float4*)(x + (size_t)n * IDIM + c4 * 4);
    *(float4*)(&xs[node][c4 * 4]) = v;
  }
  __syncthreads();
  const int node = t >> 4;
  const int lane = t & 15;
  const int n = n0 + node;
  if (n >= N) return;
  const float4* xr = (const float4*)(&xs[node][0]);
  const int nrh = Rp1 * NH;       // 72
  for (int rh = lane; rh < nrh; rh += 16) {
    const float4* qe = (const float4*)(qWe + (size_t)rh * IDIM);
    const float4* qo = (const float4*)(qWo + (size_t)rh * IDIM);
    float se0 = 0, se1 = 0, se2 = 0, se3 = 0;
    float so0 = 0, so1 = 0, so2 = 0, so3 = 0;
    #pragma unroll
    for (int d4 = 0; d4 < 32; ++d4) {
      float4 xv = xr[d4], ev = qe[d4], ov = qo[d4];
      se0 += ev.x * xv.x; se1 += ev.y * xv.y; se2 += ev.z * xv.z; se3 += ev.w * xv.w;
      so0 += ov.x * xv.x; so1 += ov.y * xv.y; so2 += ov.z * xv.z; so3 += ov.w * xv.w;
    }
    int r = rh >> 3, h = rh & 7;
    A[((size_t)r * N + n) * NH + h] = (se0 + se1) + (se2 + se3);
    B[((size_t)r * N + n) * NH + h] = (so0 + so1) + (so2 + so3);
  }
}

// ---------------------------------------------------------------------------
// zero out / wmax / normsum / cnt (harness poisons ws+out with 0xAA)
// ---------------------------------------------------------------------------
__global__ __launch_bounds__(256) void k_init(
    float* __restrict__ out, unsigned* __restrict__ wmax,
    float* __restrict__ normsum, float* __restrict__ cnt, int N) {
  int tid = blockIdx.x * 256 + threadIdx.x;
  if (tid < N * ODIM) out[tid] = 0.f;
  if (tid < N * NH) { wmax[tid] = 0u; normsum[tid] = 0.f; }
  if (tid < N) cnt[tid] = 0.f;
}

// ---------------------------------------------------------------------------
// per edge: w[h] = leaky(A[r][s][h] + B[r][d][h]); wmax atomicMax; cnt += 1
// ---------------------------------------------------------------------------
__global__ __launch_bounds__(256) void k_wmax(
    const int* __restrict__ el, const float* __restrict__ A,
    const float* __restrict__ B, unsigned* __restrict__ wmax,
    float* __restrict__ cnt, int E, int Etot, int N, int selfRel) {
  int e = blockIdx.x * 256 + threadIdx.x;
  if (e >= Etot) return;
  int s, d, r;
  if (e < E) { s = el[3 * e]; d = el[3 * e + 1]; r = el[3 * e + 2]; }
  else       { s = d = e - E; r = selfRel; }
  const float4* Ap = (const float4*)(A + ((size_t)r * N + s) * NH);
  const float4* Bp = (const float4*)(B + ((size_t)r * N + d) * NH);
  float4 a0 = Ap[0], a1 = Ap[1], b0 = Bp[0], b1 = Bp[1];
  unsigned* wm = wmax + (size_t)d * NH;
  atomicMax(&wm[0], encf(leaky(a0.x + b0.x)));
  atomicMax(&wm[1], encf(leaky(a0.y + b0.y)));
  atomicMax(&wm[2], encf(leaky(a0.z + b0.z)));
  atomicMax(&wm[3], encf(leaky(a0.w + b0.w)));
  atomicMax(&wm[4], encf(leaky(a1.x + b1.x)));
  atomicMax(&wm[5], encf(leaky(a1.y + b1.y)));
  atomicMax(&wm[6], encf(leaky(a1.z + b1.z)));
  atomicMax(&wm[7], encf(leaky(a1.w + b1.w)));
  atomicAdd(&cnt[d], 1.0f);
}

// ---------------------------------------------------------------------------
// per edge: att[h] = exp(w - wmax)*ew ; normsum[d][h] += att[h]
// ---------------------------------------------------------------------------
__global__ __launch_bounds__(256) void k_norm(
    const int* __restrict__ el, const float* __restrict__ ew,
    const float* __restrict__ A, const float* __restrict__ B,
    const unsigned* __restrict__ wmax, float* __restrict__ normsum,
    int E, int Etot, int N, int selfRel) {
  int e = blockIdx.x * 256 + threadIdx.x;
  if (e >= Etot) return;
  int s, d, r; float ewv;
  if (e < E) { s = el[3 * e]; d = el[3 * e + 1]; r = el[3 * e + 2]; ewv = ew[e]; }
  else       { s = d = e - E; r = selfRel; ewv = 1.0f; }
  const float4* Ap = (const float4*)(A + ((size_t)r * N + s) * NH);
  const float4* Bp = (const float4*)(B + ((size_t)r * N + d) * NH);
  float4 a0 = Ap[0], a1 = Ap[1], b0 = Bp[0], b1 = Bp[1];
  const unsigned* wm = wmax + (size_t)d * NH;
  float* ns = normsum + (size_t)d * NH;
  float wv[8] = {a0.x + b0.x, a0.y + b0.y, a0.z + b0.z, a0.w + b0.w,
                 a1.x + b1.x, a1.y + b1.y, a1.z + b1.z, a1.w + b1.w};
  #pragma unroll
  for (int h = 0; h < 8; ++h) {
    float att = expf(leaky(wv[h]) - decf(wm[h])) * ewv;
    atomicAdd(&ns[h], att);
  }
}

// ---------------------------------------------------------------------------
// GEMM chunk: hidden[ry][n][o] = sum_d x[n][d] * W[r0+ry][o][d]
// ---------------------------------------------------------------------------
__global__ __launch_bounds__(256) void k_hidden(
    const float* __restrict__ x, const float* __restrict__ W,
    float* __restrict__ hidden, int N, int r0, int Rp1) {
  const int ry = blockIdx.y;
  const int r  = r0 + ry;
  if (r >= Rp1) return;
  const int n0 = blockIdx.x * 32;
  __shared__ float xs[32][132];
  const int t = threadIdx.x;
  for (int i = t; i < 32 * 32; i += 256) {
    int node = i >> 5, c4 = i & 31;
    int n = n0 + node;
    float4 v = make_float4(0.f, 0.f, 0.f, 0.f);
    if (n < N) v = *(const float4*)(x + (size_t)n * IDIM + c4 * 4);
    *(float4*)(&xs[node][c4 * 4]) = v;
  }
  __syncthreads();
  const int node = t >> 3;
  const int o0   = (t & 7) * 16;
  const int n = n0 + node;
  if (n >= N) return;
  const float* Wr = W + (size_t)r * ODIM * IDIM;
  float* outp = hidden + ((size_t)ry * N + n) * ODIM + o0;
  const float4* xrow = (const float4*)(&xs[node][0]);
  #pragma unroll 1
  for (int oo = 0; oo < 16; ++oo) {
    const float4* wrow = (const float4*)(Wr + (size_t)(o0 + oo) * IDIM);
    float s0 = 0.f, s1 = 0.f, s2 = 0.f, s3 = 0.f;
    #pragma unroll
    for (int d4 = 0; d4 < 32; ++d4) {
      float4 wv = wrow[d4], xv = xrow[d4];
      s0 += wv.x * xv.x; s1 += wv.y * xv.y;
      s2 += wv.z * xv.z; s3 += wv.w * xv.w;
    }
    outp[oo] = (s0 + s1) + (s2 + s3);
  }
}

// ---------------------------------------------------------------------------
// scatter: edges with r0 <= rel < r1. 32 threads/edge, 4 floats each.
// att' = exp(w - m)*ew / (normsum/cnt + EPS); out[d] += att' * hidden[rel][s]
// ---------------------------------------------------------------------------
__global__ __launch_bounds__(256) void k_scatter(
    const int* __restrict__ el, const float* __restrict__ ew,
    const float* __restrict__ A, const float* __restrict__ B,
    const unsigned* __restrict__ wmax, const float* __restrict__ normsum,
    const float* __restrict__ cnt, const float* __restrict__ hidden,
    float* __restrict__ out, int E, int Etot, int N, int selfRel,
    int r0, int r1) {
  int tid = blockIdx.x * 256 + threadIdx.x;
  int e = tid >> 5, o4 = tid & 31;
  if (e >= Etot) return;
  int s, d, r; float ewv;
  if (e < E) { s = el[3 * e]; d = el[3 * e + 1]; r = el[3 * e + 2]; ewv = ew[e]; }
  else       { s = d = e - E; r = selfRel; ewv = 1.0f; }
  if (r < r0 || r >= r1) return;
  int h = o4 >> 2;
  float a = A[((size_t)r * N + s) * NH + h];
  float b = B[((size_t)r * N + d) * NH + h];
  float w = leaky(a + b);
  float m = decf(wmax[(size_t)d * NH + h]);
  float att = expf(w - m) * ewv;
  float c  = cnt[d];
  float ns = normsum[(size_t)d * NH + h];
  float attp = att / (ns / c + EPSV);
  const float4 v = *(const float4*)(hidden + ((size_t)(r - r0) * N + s) * ODIM + o4 * 4);
  float* op = out + (size_t)d * ODIM + o4 * 4;
  atomicAdd(op + 0, attp * v.x);
  atomicAdd(op + 1, attp * v.y);
  atomicAdd(op + 2, attp * v.z);
  atomicAdd(op + 3, attp * v.w);
}

// ---------------------------------------------------------------------------
// out = relu(out / cnt)
// ---------------------------------------------------------------------------
__global__ __launch_bounds__(256) void k_fin(
    float* __restrict__ out, const float* __restrict__ cnt, int total) {
  int tid = blockIdx.x * 256 + threadIdx.x;
  if (tid >= total) return;
  int n = tid >> 7;
  float v = out[tid] / cnt[n];
  out[tid] = v > 0.f ? v : 0.f;
}

extern "C" void kernel_launch(void* const* d_in, const int* in_sizes, int n_in,
                              void* d_out, int out_size, void* d_ws, size_t ws_size,
                              hipStream_t stream) {
  const float* x     = (const float*)d_in[0];
  const int*   el    = (const int*)d_in[1];
  const float* ew    = (const float*)d_in[2];
  const float* W     = (const float*)d_in[3];
  const float* query = (const float*)d_in[4];
  const int N    = in_sizes[0] / IDIM;
  const int E    = in_sizes[1] / 3;
  const int Rp1  = in_sizes[3] / (ODIM * IDIM);
  const int Etot = E + N;
  const int selfRel = Rp1 - 1;
  float* out = (float*)d_out;

  // ---- workspace carve-up (ws_size-adaptive) ----
  auto align256 = [](size_t v) { return (v + 255) & ~(size_t)255; };
  char* ws = (char*)d_ws;
  size_t off = 0;
  const size_t ab_bytes   = align256((size_t)Rp1 * N * NH * 4);
  const size_t qw_bytes   = align256((size_t)Rp1 * NH * IDIM * 4);
  const size_t wmax_bytes = align256((size_t)N * NH * 4);
  const size_t cnt_bytes  = align256((size_t)N * 4);
  const size_t per_rel    = (size_t)N * ODIM * 4;

  float*    A       = (float*)(ws + off);    off += ab_bytes;
  float*    B       = (float*)(ws + off);    off += ab_bytes;
  float*    qWe     = (float*)(ws + off);    off += qw_bytes;
  float*    qWo     = (float*)(ws + off);    off += qw_bytes;
  unsigned* wmax    = (unsigned*)(ws + off); off += wmax_bytes;
  float*    normsum = (float*)(ws + off);    off += wmax_bytes;
  float*    cnt     = (float*)(ws + off);    off += cnt_bytes;
  float*    hidden  = (float*)(ws + off);    // chunk buffer, RC relations

  // relations resident at once, bounded by remaining ws
  int RC = 1;
  if (ws_size > off + per_rel) {
    size_t fit = (ws_size - off) / per_rel;
    RC = (int)(fit < (size_t)Rp1 ? fit : (size_t)Rp1);
    if (RC < 1) RC = 1;
  }

  // ---- launches ----
  int qw_total = Rp1 * NH * IDIM;
  k_qw<<<(qw_total + 255) / 256, 256, 0, stream>>>(W, query, qWe, qWo, qw_total);
  k_AB<<<(N + 15) / 16, 256, 0, stream>>>(x, qWe, qWo, A, B, N, Rp1);
  k_init<<<(N * ODIM + 255) / 256, 256, 0, stream>>>(out, wmax, normsum, cnt, N);
  k_wmax<<<(Etot + 255) / 256, 256, 0, stream>>>(el, A, B, wmax, cnt, E, Etot, N, selfRel);
  k_norm<<<(Etot + 255) / 256, 256, 0, stream>>>(el, ew, A, B, wmax, normsum, E, Etot, N, selfRel);

  long long nsc = (long long)Etot * 32;
  int sc_blocks = (int)((nsc + 255) / 256);
  for (int r0 = 0; r0 < Rp1; r0 += RC) {
    int rc = (r0 + RC <= Rp1) ? RC : (Rp1 - r0);
    dim3 gh((N + 31) / 32, rc);
    k_hidden<<<gh, 256, 0, stream>>>(x, W, hidden, N, r0, Rp1);
    k_scatter<<<sc_blocks, 256, 0, stream>>>(el, ew, A, B, wmax, normsum, cnt,
                                             hidden, out, E, Etot, N, selfRel,
                                             r0, r0 + rc);
  }
  k_fin<<<(N * ODIM + 255) / 256, 256, 0, stream>>>(out, cnt, N * ODIM);
}